// Round 2
// baseline (1764.501 us; speedup 1.0000x reference)
//
#include <hip/hip_runtime.h>
#include <hip/hip_bf16.h>
#include <math.h>

#define BATCH   2
#define SEQLEN  2048
#define D_MODEL 1024
#define D_INNER 2048
#define D_STATE 16
#define NROW    (BATCH * SEQLEN)   // 4096
#define EPSF    1e-10f

typedef unsigned short ushort_t;
typedef __attribute__((ext_vector_type(8))) short short8;
typedef __attribute__((ext_vector_type(4))) float f32x4;

__device__ __forceinline__ float bf2f(ushort_t u) {
    union { unsigned int i; float f; } v; v.i = ((unsigned int)u) << 16; return v.f;
}
__device__ __forceinline__ ushort_t f2bf(float f) {
    union { float f; unsigned int i; } v; v.f = f;
    unsigned int r = v.i + 0x7FFFu + ((v.i >> 16) & 1u);   // RNE
    return (ushort_t)(r >> 16);
}

// 8 contiguous elements -> bf16 short8 (for LDS staging)
__device__ __forceinline__ short8 ld8bf(const ushort_t* p) {
    return *(const short8*)p;
}
__device__ __forceinline__ short8 ld8bf(const float* p) {
    f32x4 a = ((const f32x4*)p)[0];
    f32x4 b = ((const f32x4*)p)[1];
    short8 r;
    r[0] = (short)f2bf(a[0]); r[1] = (short)f2bf(a[1]);
    r[2] = (short)f2bf(a[2]); r[3] = (short)f2bf(a[3]);
    r[4] = (short)f2bf(b[0]); r[5] = (short)f2bf(b[1]);
    r[6] = (short)f2bf(b[2]); r[7] = (short)f2bf(b[3]);
    return r;
}
__device__ __forceinline__ void st1(float* p, float v)    { *p = v; }
__device__ __forceinline__ void st1(ushort_t* p, float v) { *p = f2bf(v); }

// ---------------------------------------------------------------------------
// GEMM: C[M,N] = A[M,K] @ B[N,K]^T.  A/B fp32 or bf16 (converted to bf16 in
// LDS staging), fp32 MFMA accum, C fp32 or bf16.  128x128 tile, 4 waves 2x2,
// each wave 64x64 via 4x4 mfma_f32_16x16x32_bf16.  LDS rows padded to 40
// shorts (80 B) -> at most 2-way bank aliasing (free).
// ---------------------------------------------------------------------------
template<int K, typename TA, typename TB, typename TC>
__global__ __launch_bounds__(256) void gemm_bt(const TA* __restrict__ A,
                                               const TB* __restrict__ B,
                                               TC* __restrict__ C, int N) {
    __shared__ alignas(16) ushort_t As[128][40];
    __shared__ alignas(16) ushort_t Bs[128][40];
    const int tid  = threadIdx.x;
    const int wave = tid >> 6, lane = tid & 63;
    const int wm = (wave >> 1) * 64, wn = (wave & 1) * 64;
    const int row0 = blockIdx.y * 128, col0 = blockIdx.x * 128;
    f32x4 acc[4][4] = {};
    const int srow = tid >> 2;          // 0..63
    const int sk   = (tid & 3) * 8;     // 0,8,16,24 (elements)
    const int fr   = lane & 15;
    const int fk   = (lane >> 4) * 8;   // 0,8,16,24 (shorts)
    for (int k0 = 0; k0 < K; k0 += 32) {
        *(short8*)&As[srow][sk]      = ld8bf(&A[(size_t)(row0 + srow)      * K + k0 + sk]);
        *(short8*)&As[srow + 64][sk] = ld8bf(&A[(size_t)(row0 + srow + 64) * K + k0 + sk]);
        *(short8*)&Bs[srow][sk]      = ld8bf(&B[(size_t)(col0 + srow)      * K + k0 + sk]);
        *(short8*)&Bs[srow + 64][sk] = ld8bf(&B[(size_t)(col0 + srow + 64) * K + k0 + sk]);
        __syncthreads();
        short8 af[4], bfr[4];
        #pragma unroll
        for (int i = 0; i < 4; ++i) {
            af[i]  = *(const short8*)&As[wm + i * 16 + fr][fk];
            bfr[i] = *(const short8*)&Bs[wn + i * 16 + fr][fk];
        }
        #pragma unroll
        for (int i = 0; i < 4; ++i)
            #pragma unroll
            for (int j = 0; j < 4; ++j)
                acc[i][j] = __builtin_amdgcn_mfma_f32_16x16x32_bf16(af[i], bfr[j], acc[i][j], 0, 0, 0);
        __syncthreads();
    }
    const int quad = lane >> 4;
    #pragma unroll
    for (int i = 0; i < 4; ++i)
        #pragma unroll
        for (int j = 0; j < 4; ++j)
            #pragma unroll
            for (int r = 0; r < 4; ++r) {
                // m89-verified C/D layout: col = lane&15, row = (lane>>4)*4 + reg
                int row = row0 + wm + i * 16 + quad * 4 + r;
                int col = col0 + wn + j * 16 + fr;
                st1(&C[(size_t)row * N + col], acc[i][j][r]);
            }
}

// ---------------------------------------------------------------------------
// Depthwise causal conv (k=4) + bias + SiLU.  xi = xz[:, :D_INNER] (bf16).
// Weights/bias fp32.  Thread handles 4 consecutive channels of one (b,t) row.
// ---------------------------------------------------------------------------
__global__ __launch_bounds__(256) void conv_silu_k(const ushort_t* __restrict__ xz,
                                                   const float* __restrict__ cw,
                                                   const float* __restrict__ cb,
                                                   ushort_t* __restrict__ xc) {
    int idx = blockIdx.x * 256 + threadIdx.x;        // over NROW * (D_INNER/4)
    int d4  = (idx & (D_INNER / 4 - 1)) * 4;
    int row = idx >> 9;                              // /(D_INNER/4)
    int t   = row & (SEQLEN - 1);
    float a[4] = {0.f, 0.f, 0.f, 0.f};
    #pragma unroll
    for (int j = 0; j < 4; ++j) {
        int tt = t - 3 + j;
        if (tt >= 0) {
            const ushort_t* p = &xz[(size_t)(row - 3 + j) * (2 * D_INNER) + d4];
            #pragma unroll
            for (int u = 0; u < 4; ++u)
                a[u] += cw[(d4 + u) * 4 + j] * bf2f(p[u]);
        }
    }
    #pragma unroll
    for (int u = 0; u < 4; ++u) {
        float v  = a[u] + cb[d4 + u];
        float sv = v / (1.f + expf(-v));             // SiLU
        xc[(size_t)row * D_INNER + d4 + u] = f2bf(sv);
    }
}

// ---------------------------------------------------------------------------
// x_proj: xp[row, 0:33] = xc[row,:] @ x_proj_w[33, 2048]^T  (fp32 out).
// One wave per row, butterfly reduce.  xc bf16, w fp32.
// ---------------------------------------------------------------------------
__global__ __launch_bounds__(256) void xproj_k(const ushort_t* __restrict__ xc,
                                               const float* __restrict__ w,
                                               float* __restrict__ xp) {
    int row  = blockIdx.x * 4 + (threadIdx.x >> 6);
    int lane = threadIdx.x & 63;
    const ushort_t* xr = xc + (size_t)row * D_INNER;
    float xf[32];
    #pragma unroll
    for (int c = 0; c < 4; ++c) {
        short8 xv = *(const short8*)&xr[c * 512 + lane * 8];
        #pragma unroll
        for (int u = 0; u < 8; ++u) xf[c * 8 + u] = bf2f((ushort_t)xv[u]);
    }
    for (int j = 0; j < 33; ++j) {
        float acc = 0.f;
        #pragma unroll
        for (int c = 0; c < 4; ++c) {
            const f32x4* wp = (const f32x4*)&w[(size_t)j * D_INNER + c * 512 + lane * 8];
            f32x4 w0 = wp[0], w1 = wp[1];
            #pragma unroll
            for (int u = 0; u < 4; ++u) acc += xf[c * 8 + u]     * w0[u];
            #pragma unroll
            for (int u = 0; u < 4; ++u) acc += xf[c * 8 + 4 + u] * w1[u];
        }
        acc += __shfl_xor(acc, 32); acc += __shfl_xor(acc, 16);
        acc += __shfl_xor(acc, 8);  acc += __shfl_xor(acc, 4);
        acc += __shfl_xor(acc, 2);  acc += __shfl_xor(acc, 1);
        if (lane == 0) xp[(size_t)row * 33 + j] = acc;
    }
}

// ---------------------------------------------------------------------------
// Selective scan, replicating the reference's chunked formulation with its
// EPS clamps.  Identities (ulp-level exact vs reference):
//   exp(cumsum(log(max(Abar,EPS))))  == running prod of fmax(Abar,EPS)
//   A_cum*wcum/max(Abar,EPS)         == prevA*wcum
// Per chunk of 256:  Acum *= fmax(exp(delta*A),EPS);
//   wc += BX / fmax(prevA,EPS);  h = prevA*wc + h0*Acum;  h0 <- h at chunk end.
// Lane = (channel, state): 16 channels x 16 states per block.  1-deep
// software prefetch of t+1 loads.  Fused epilogue: G = (C.h + D*x) * silu(z),
// written IN PLACE over xc (read-before-write within the wave: safe).
// ---------------------------------------------------------------------------
__global__ __launch_bounds__(256) void scan_k(const ushort_t* __restrict__ xc,
                                              const float* __restrict__ xp,
                                              const ushort_t* __restrict__ xz,
                                              const float* __restrict__ dt_w,
                                              const float* __restrict__ dt_b,
                                              const float* __restrict__ A_log,
                                              const float* __restrict__ D_par,
                                              ushort_t* __restrict__ G) {
    const int tid = threadIdx.x;
    const int s   = tid & 15;
    const int ch  = blockIdx.x * 16 + (tid >> 4);   // 0..4095
    const int b   = ch >> 11;                        // /D_INNER
    const int d   = ch & (D_INNER - 1);
    const float A_s = -expf(A_log[s]);
    const float dtw = dt_w[d];
    const float dtb = dt_b[d];
    const float Dp  = D_par[d];
    float h0 = 0.f, Acum = 1.f, wc = 0.f;
    const int rowbase = b * SEQLEN;
    const float* xpr  = xp + (size_t)rowbase * 33;
    const ushort_t* xcr = xc + (size_t)rowbase * D_INNER + d;
    const ushort_t* xzr = xz + (size_t)rowbase * (2 * D_INNER) + D_INNER + d;
    ushort_t* Gr = G + (size_t)rowbase * D_INNER + d;
    float xp0 = xpr[0], Bv = xpr[1 + s], Cv = xpr[17 + s];
    float xcv = bf2f(xcr[0]);
    float zv  = bf2f(xzr[0]);
    for (int t = 0; t < SEQLEN; ++t) {
        float xp0n = 0.f, Bvn = 0.f, Cvn = 0.f, xcvn = 0.f, zvn = 0.f;
        if (t + 1 < SEQLEN) {                       // prefetch t+1
            const float* np = xpr + 33;
            xp0n = np[0]; Bvn = np[1 + s]; Cvn = np[17 + s];
            xcvn = bf2f(xcr[D_INNER]);
            zvn  = bf2f(xzr[2 * D_INNER]);
        }
        const float u     = xp0 * dtw + dtb;
        const float delta = fmaxf(u, 0.f) + log1pf(expf(-fabsf(u)));  // softplus
        const float Ab    = fmaxf(expf(delta * A_s), EPSF);
        const float prevA = Acum;
        Acum *= Ab;
        wc += (delta * Bv * xcv) / fmaxf(prevA, EPSF);
        const float h = prevA * wc + h0 * Acum;
        float ys = Cv * h;
        ys += __shfl_xor(ys, 1); ys += __shfl_xor(ys, 2);
        ys += __shfl_xor(ys, 4); ys += __shfl_xor(ys, 8);
        if (s == 0) {
            const float y = ys + Dp * xcv;
            const float g = y * (zv / (1.f + expf(-zv)));
            Gr[0] = f2bf(g);
        }
        if ((t & 255) == 255) { h0 = h; Acum = 1.f; wc = 0.f; }
        xp0 = xp0n; Bv = Bvn; Cv = Cvn; xcv = xcvn; zv = zvn;
        xpr += 33; xcr += D_INNER; xzr += 2 * D_INNER; Gr += D_INNER;
    }
}

// ---------------------------------------------------------------------------
extern "C" void kernel_launch(void* const* d_in, const int* in_sizes, int n_in,
                              void* d_out, int out_size, void* d_ws, size_t ws_size,
                              hipStream_t stream) {
    const float* x     = (const float*)d_in[0];
    const float* w_in  = (const float*)d_in[1];
    const float* cw    = (const float*)d_in[2];
    const float* cb    = (const float*)d_in[3];
    const float* w_xp  = (const float*)d_in[4];
    const float* dtw   = (const float*)d_in[5];
    const float* dtb   = (const float*)d_in[6];
    const float* alog  = (const float*)d_in[7];
    const float* dpar  = (const float*)d_in[8];
    const float* w_out = (const float*)d_in[9];
    float* out = (float*)d_out;

    char* ws = (char*)d_ws;
    ushort_t* xz = (ushort_t*)ws;                              // 4096*4096 bf16 = 32 MB
    ushort_t* xc = (ushort_t*)(ws + 32ull * 1024 * 1024);      // 4096*2048 bf16 = 16 MB
    float*    xp = (float*)   (ws + 48ull * 1024 * 1024);      // 4096*33 fp32 ~ 0.54 MB
    ushort_t* G  = xc;                                         // in-place over xc

    // 1) xz = x @ in_proj_w^T   (M=4096, N=4096, K=1024)  fp32 in, bf16 out
    hipLaunchKernelGGL((gemm_bt<D_MODEL, float, float, ushort_t>),
                       dim3(2 * D_INNER / 128, NROW / 128), dim3(256), 0, stream,
                       x, w_in, xz, 2 * D_INNER);
    // 2) xc = silu(causal depthwise conv(xi) + cb)
    hipLaunchKernelGGL(conv_silu_k, dim3(NROW * (D_INNER / 4) / 256), dim3(256), 0, stream,
                       xz, cw, cb, xc);
    // 3) xp = xc @ x_proj_w^T   (fp32, width 33)
    hipLaunchKernelGGL(xproj_k, dim3(NROW / 4), dim3(256), 0, stream, xc, w_xp, xp);
    // 4) selective scan + gating -> G = (y) * silu(z)   (in place over xc)
    hipLaunchKernelGGL(scan_k, dim3(BATCH * D_INNER / 16), dim3(256), 0, stream,
                       xc, xp, xz, dtw, dtb, alog, dpar, G);
    // 5) out = G @ out_proj_w^T  (M=4096, N=1024, K=2048)  bf16/fp32 in, fp32 out
    hipLaunchKernelGGL((gemm_bt<D_INNER, ushort_t, float, float>),
                       dim3(D_MODEL / 128, NROW / 128), dim3(256), 0, stream,
                       G, w_out, out, D_MODEL);
    (void)in_sizes; (void)n_in; (void)out_size; (void)ws_size;
}

// Round 3
// 702.864 us; speedup vs baseline: 2.5104x; 2.5104x over previous
//
#include <hip/hip_runtime.h>
#include <hip/hip_bf16.h>
#include <math.h>

#define BATCH   2
#define SEQLEN  2048
#define D_MODEL 1024
#define D_INNER 2048
#define D_STATE 16
#define NCHUNK  8
#define CHUNKT  256
#define NROW    (BATCH * SEQLEN)   // 4096
#define NCH     (BATCH * D_INNER)  // 4096 channels
#define EPSF    1e-10f

typedef unsigned short ushort_t;
typedef __attribute__((ext_vector_type(8))) short short8;
typedef __attribute__((ext_vector_type(4))) float f32x4;

__device__ __forceinline__ float bf2f(ushort_t u) {
    union { unsigned int i; float f; } v; v.i = ((unsigned int)u) << 16; return v.f;
}
__device__ __forceinline__ ushort_t f2bf(float f) {
    union { float f; unsigned int i; } v; v.f = f;
    unsigned int r = v.i + 0x7FFFu + ((v.i >> 16) & 1u);   // RNE
    return (ushort_t)(r >> 16);
}
__device__ __forceinline__ float frcp(float x) {
#if __has_builtin(__builtin_amdgcn_rcpf)
    return __builtin_amdgcn_rcpf(x);
#else
    return 1.0f / x;
#endif
}

// 8 contiguous elements -> bf16 short8 (for LDS staging)
__device__ __forceinline__ short8 ld8bf(const ushort_t* p) {
    return *(const short8*)p;
}
__device__ __forceinline__ short8 ld8bf(const float* p) {
    f32x4 a = ((const f32x4*)p)[0];
    f32x4 b = ((const f32x4*)p)[1];
    short8 r;
    r[0] = (short)f2bf(a[0]); r[1] = (short)f2bf(a[1]);
    r[2] = (short)f2bf(a[2]); r[3] = (short)f2bf(a[3]);
    r[4] = (short)f2bf(b[0]); r[5] = (short)f2bf(b[1]);
    r[6] = (short)f2bf(b[2]); r[7] = (short)f2bf(b[3]);
    return r;
}
__device__ __forceinline__ void st1(float* p, float v)    { *p = v; }
__device__ __forceinline__ void st1(ushort_t* p, float v) { *p = f2bf(v); }

// ---------------------------------------------------------------------------
// GEMM: C[M,N] = A[M,K] @ B[N,K]^T (unchanged from round 2 — known correct).
// ---------------------------------------------------------------------------
template<int K, typename TA, typename TB, typename TC>
__global__ __launch_bounds__(256) void gemm_bt(const TA* __restrict__ A,
                                               const TB* __restrict__ B,
                                               TC* __restrict__ C, int N) {
    __shared__ alignas(16) ushort_t As[128][40];
    __shared__ alignas(16) ushort_t Bs[128][40];
    const int tid  = threadIdx.x;
    const int wave = tid >> 6, lane = tid & 63;
    const int wm = (wave >> 1) * 64, wn = (wave & 1) * 64;
    const int row0 = blockIdx.y * 128, col0 = blockIdx.x * 128;
    f32x4 acc[4][4] = {};
    const int srow = tid >> 2;
    const int sk   = (tid & 3) * 8;
    const int fr   = lane & 15;
    const int fk   = (lane >> 4) * 8;
    for (int k0 = 0; k0 < K; k0 += 32) {
        *(short8*)&As[srow][sk]      = ld8bf(&A[(size_t)(row0 + srow)      * K + k0 + sk]);
        *(short8*)&As[srow + 64][sk] = ld8bf(&A[(size_t)(row0 + srow + 64) * K + k0 + sk]);
        *(short8*)&Bs[srow][sk]      = ld8bf(&B[(size_t)(col0 + srow)      * K + k0 + sk]);
        *(short8*)&Bs[srow + 64][sk] = ld8bf(&B[(size_t)(col0 + srow + 64) * K + k0 + sk]);
        __syncthreads();
        short8 af[4], bfr[4];
        #pragma unroll
        for (int i = 0; i < 4; ++i) {
            af[i]  = *(const short8*)&As[wm + i * 16 + fr][fk];
            bfr[i] = *(const short8*)&Bs[wn + i * 16 + fr][fk];
        }
        #pragma unroll
        for (int i = 0; i < 4; ++i)
            #pragma unroll
            for (int j = 0; j < 4; ++j)
                acc[i][j] = __builtin_amdgcn_mfma_f32_16x16x32_bf16(af[i], bfr[j], acc[i][j], 0, 0, 0);
        __syncthreads();
    }
    const int quad = lane >> 4;
    #pragma unroll
    for (int i = 0; i < 4; ++i)
        #pragma unroll
        for (int j = 0; j < 4; ++j)
            #pragma unroll
            for (int r = 0; r < 4; ++r) {
                int row = row0 + wm + i * 16 + quad * 4 + r;
                int col = col0 + wn + j * 16 + fr;
                st1(&C[(size_t)row * N + col], acc[i][j][r]);
            }
}

// ---------------------------------------------------------------------------
// Depthwise causal conv (k=4) + bias + SiLU (unchanged).
// ---------------------------------------------------------------------------
__global__ __launch_bounds__(256) void conv_silu_k(const ushort_t* __restrict__ xz,
                                                   const float* __restrict__ cw,
                                                   const float* __restrict__ cb,
                                                   ushort_t* __restrict__ xc) {
    int idx = blockIdx.x * 256 + threadIdx.x;
    int d4  = (idx & (D_INNER / 4 - 1)) * 4;
    int row = idx >> 9;
    int t   = row & (SEQLEN - 1);
    float a[4] = {0.f, 0.f, 0.f, 0.f};
    #pragma unroll
    for (int j = 0; j < 4; ++j) {
        int tt = t - 3 + j;
        if (tt >= 0) {
            const ushort_t* p = &xz[(size_t)(row - 3 + j) * (2 * D_INNER) + d4];
            #pragma unroll
            for (int u = 0; u < 4; ++u)
                a[u] += cw[(d4 + u) * 4 + j] * bf2f(p[u]);
        }
    }
    #pragma unroll
    for (int u = 0; u < 4; ++u) {
        float v  = a[u] + cb[d4 + u];
        float sv = v / (1.f + expf(-v));
        xc[(size_t)row * D_INNER + d4 + u] = f2bf(sv);
    }
}

// ---------------------------------------------------------------------------
// x_proj (unchanged).
// ---------------------------------------------------------------------------
__global__ __launch_bounds__(256) void xproj_k(const ushort_t* __restrict__ xc,
                                               const float* __restrict__ w,
                                               float* __restrict__ xp) {
    int row  = blockIdx.x * 4 + (threadIdx.x >> 6);
    int lane = threadIdx.x & 63;
    const ushort_t* xr = xc + (size_t)row * D_INNER;
    float xf[32];
    #pragma unroll
    for (int c = 0; c < 4; ++c) {
        short8 xv = *(const short8*)&xr[c * 512 + lane * 8];
        #pragma unroll
        for (int u = 0; u < 8; ++u) xf[c * 8 + u] = bf2f((ushort_t)xv[u]);
    }
    for (int j = 0; j < 33; ++j) {
        float acc = 0.f;
        #pragma unroll
        for (int c = 0; c < 4; ++c) {
            const f32x4* wp = (const f32x4*)&w[(size_t)j * D_INNER + c * 512 + lane * 8];
            f32x4 w0 = wp[0], w1 = wp[1];
            #pragma unroll
            for (int u = 0; u < 4; ++u) acc += xf[c * 8 + u]     * w0[u];
            #pragma unroll
            for (int u = 0; u < 4; ++u) acc += xf[c * 8 + 4 + u] * w1[u];
        }
        acc += __shfl_xor(acc, 32); acc += __shfl_xor(acc, 16);
        acc += __shfl_xor(acc, 8);  acc += __shfl_xor(acc, 4);
        acc += __shfl_xor(acc, 2);  acc += __shfl_xor(acc, 1);
        if (lane == 0) xp[(size_t)row * 33 + j] = acc;
    }
}

// ---------------------------------------------------------------------------
// Chunk-parallel selective scan.  The per-chunk recurrence (identical ops to
// the round-2 validated kernel) is affine in the entering state h0:
//   h_end = P*h0 + q,  P = Acum(255),  q = prevA(255)*wc(255).
// Pass 1 computes (P,q) for all 8 chunks in parallel; combine_k does the
// 8-step sequential chunk chain per (ch,s); pass 2 replays each chunk with
// its h0 and emits G = (C.h + D*x)*silu(z).
// Lane layout: s = tid&15 (state), dloc = tid>>4 (channel in block of 16).
// ---------------------------------------------------------------------------
__device__ __forceinline__ float softplus_f(float u) {
    return fmaxf(u, 0.f) + __logf(1.f + __expf(-fabsf(u)));
}

__global__ __launch_bounds__(256) void scan_p1(const ushort_t* __restrict__ xc,
                                               const float* __restrict__ xp,
                                               const float* __restrict__ dt_w,
                                               const float* __restrict__ dt_b,
                                               const float* __restrict__ A_log,
                                               float* __restrict__ Pbuf,
                                               float* __restrict__ qbuf) {
    const int tid = threadIdx.x;
    const int s   = tid & 15;
    const int ch  = blockIdx.x * 16 + (tid >> 4);   // 0..4095
    const int c   = blockIdx.y;                      // chunk
    const int b   = ch >> 11;
    const int d   = ch & (D_INNER - 1);
    const float A_s = -__expf(A_log[s]);
    const float dtw = dt_w[d];
    const float dtb = dt_b[d];
    const int rowbase = b * SEQLEN + c * CHUNKT;
    const float*    xpr = xp + (size_t)rowbase * 33;
    const ushort_t* xcr = xc + (size_t)rowbase * D_INNER + d;
    float Acum = 1.f, wc = 0.f, prevA = 1.f;
    for (int t = 0; t < CHUNKT; ++t) {
        const float xp0 = xpr[0];
        const float Bv  = xpr[1 + s];
        const float xcv = bf2f(xcr[0]);
        const float delta = softplus_f(fmaf(xp0, dtw, dtb));
        const float Ab    = fmaxf(__expf(delta * A_s), EPSF);
        prevA = Acum;
        Acum  = prevA * Ab;
        wc    = fmaf(delta * Bv * xcv, frcp(fmaxf(prevA, EPSF)), wc);
        xpr += 33; xcr += D_INNER;
    }
    const size_t base = ((size_t)c * NCH + ch) * 16 + s;
    Pbuf[base] = Acum;
    qbuf[base] = prevA * wc;
}

__global__ __launch_bounds__(256) void combine_k(const float* __restrict__ Pbuf,
                                                 const float* __restrict__ qbuf,
                                                 float* __restrict__ hbuf) {
    const int i = blockIdx.x * 256 + threadIdx.x;    // ch*16+s, 0..65535
    float h = 0.f;
    #pragma unroll
    for (int c = 0; c < NCHUNK; ++c) {
        const size_t idx = (size_t)c * (NCH * 16) + i;
        hbuf[idx] = h;                               // state ENTERING chunk c
        h = fmaf(Pbuf[idx], h, qbuf[idx]);
    }
}

__global__ __launch_bounds__(256) void scan_p2(const ushort_t* __restrict__ xc,
                                               const float* __restrict__ xp,
                                               const ushort_t* __restrict__ xz,
                                               const float* __restrict__ dt_w,
                                               const float* __restrict__ dt_b,
                                               const float* __restrict__ A_log,
                                               const float* __restrict__ D_par,
                                               const float* __restrict__ hbuf,
                                               ushort_t* __restrict__ G) {
    const int tid = threadIdx.x;
    const int s   = tid & 15;
    const int ch  = blockIdx.x * 16 + (tid >> 4);
    const int c   = blockIdx.y;
    const int b   = ch >> 11;
    const int d   = ch & (D_INNER - 1);
    const float A_s = -__expf(A_log[s]);
    const float dtw = dt_w[d];
    const float dtb = dt_b[d];
    const float Dp  = D_par[d];
    const float h0  = hbuf[((size_t)c * NCH + ch) * 16 + s];
    const int rowbase = b * SEQLEN + c * CHUNKT;
    const float*    xpr = xp + (size_t)rowbase * 33;
    const ushort_t* xcr = xc + (size_t)rowbase * D_INNER + d;
    const ushort_t* xzr = xz + (size_t)rowbase * (2 * D_INNER) + D_INNER + d;
    ushort_t*       Gr  = G  + (size_t)rowbase * D_INNER + d;
    float Acum = 1.f, wc = 0.f;
    for (int t = 0; t < CHUNKT; ++t) {
        const float xp0 = xpr[0];
        const float Bv  = xpr[1 + s];
        const float Cv  = xpr[17 + s];
        const float xcv = bf2f(xcr[0]);
        const float delta = softplus_f(fmaf(xp0, dtw, dtb));
        const float Ab    = fmaxf(__expf(delta * A_s), EPSF);
        const float prevA = Acum;
        Acum = prevA * Ab;
        wc   = fmaf(delta * Bv * xcv, frcp(fmaxf(prevA, EPSF)), wc);
        const float h  = fmaf(prevA, wc, h0 * Acum);
        float ys = Cv * h;
        ys += __shfl_xor(ys, 1); ys += __shfl_xor(ys, 2);
        ys += __shfl_xor(ys, 4); ys += __shfl_xor(ys, 8);
        if (s == 0) {
            const float zv = bf2f(xzr[0]);
            const float y  = fmaf(Dp, xcv, ys);
            const float g  = y * zv * frcp(1.f + __expf(-zv));
            Gr[0] = f2bf(g);
        }
        xpr += 33; xcr += D_INNER; xzr += 2 * D_INNER; Gr += D_INNER;
    }
}

// ---------------------------------------------------------------------------
extern "C" void kernel_launch(void* const* d_in, const int* in_sizes, int n_in,
                              void* d_out, int out_size, void* d_ws, size_t ws_size,
                              hipStream_t stream) {
    const float* x     = (const float*)d_in[0];
    const float* w_in  = (const float*)d_in[1];
    const float* cw    = (const float*)d_in[2];
    const float* cb    = (const float*)d_in[3];
    const float* w_xp  = (const float*)d_in[4];
    const float* dtw   = (const float*)d_in[5];
    const float* dtb   = (const float*)d_in[6];
    const float* alog  = (const float*)d_in[7];
    const float* dpar  = (const float*)d_in[8];
    const float* w_out = (const float*)d_in[9];
    float* out = (float*)d_out;

    char* ws = (char*)d_ws;
    ushort_t* xz   = (ushort_t*)ws;                               // 32 MB
    ushort_t* xc   = (ushort_t*)(ws + 33554432ull);               // 16 MB
    float*    xp   = (float*)   (ws + 50331648ull);               // 0.54 MB
    float*    Pbuf = (float*)   (ws + 51380224ull);               // 2 MB
    float*    qbuf = (float*)   (ws + 53477376ull);               // 2 MB
    float*    hbuf = (float*)   (ws + 55574528ull);               // 2 MB
    ushort_t* G    = xc;                                          // in-place

    // 1) xz = x @ in_proj_w^T   (M=4096, N=4096, K=1024)
    hipLaunchKernelGGL((gemm_bt<D_MODEL, float, float, ushort_t>),
                       dim3(2 * D_INNER / 128, NROW / 128), dim3(256), 0, stream,
                       x, w_in, xz, 2 * D_INNER);
    // 2) xc = silu(causal depthwise conv(xi) + cb)
    hipLaunchKernelGGL(conv_silu_k, dim3(NROW * (D_INNER / 4) / 256), dim3(256), 0, stream,
                       xz, cw, cb, xc);
    // 3) xp = xc @ x_proj_w^T
    hipLaunchKernelGGL(xproj_k, dim3(NROW / 4), dim3(256), 0, stream, xc, w_xp, xp);
    // 4a) per-chunk (P,q)
    hipLaunchKernelGGL(scan_p1, dim3(NCH / 16, NCHUNK), dim3(256), 0, stream,
                       xc, xp, dtw, dtb, alog, Pbuf, qbuf);
    // 4b) chunk chain -> h0 per chunk
    hipLaunchKernelGGL(combine_k, dim3(NCH * 16 / 256), dim3(256), 0, stream,
                       Pbuf, qbuf, hbuf);
    // 4c) replay with h0, emit G (in place over xc)
    hipLaunchKernelGGL(scan_p2, dim3(NCH / 16, NCHUNK), dim3(256), 0, stream,
                       xc, xp, xz, dtw, dtb, alog, dpar, hbuf, G);
    // 5) out = G @ out_proj_w^T  (M=4096, N=1024, K=2048)
    hipLaunchKernelGGL((gemm_bt<D_INNER, ushort_t, float, float>),
                       dim3(D_MODEL / 128, NROW / 128), dim3(256), 0, stream,
                       G, w_out, out, D_MODEL);
    (void)in_sizes; (void)n_in; (void)out_size; (void)ws_size;
}

// Round 4
// 618.191 us; speedup vs baseline: 2.8543x; 1.1370x over previous
//
#include <hip/hip_runtime.h>
#include <hip/hip_bf16.h>
#include <math.h>

#define BATCH   2
#define SEQLEN  2048
#define D_MODEL 1024
#define D_INNER 2048
#define D_STATE 16
#define NCHUNK  8
#define CHUNKT  256
#define NROW    (BATCH * SEQLEN)   // 4096
#define NCH     (BATCH * D_INNER)  // 4096 channels
#define EPSF    1e-10f

typedef unsigned short ushort_t;
typedef __attribute__((ext_vector_type(8))) short short8;
typedef __attribute__((ext_vector_type(4))) float f32x4;

__device__ __forceinline__ float bf2f(ushort_t u) {
    union { unsigned int i; float f; } v; v.i = ((unsigned int)u) << 16; return v.f;
}
__device__ __forceinline__ ushort_t f2bf(float f) {
    union { float f; unsigned int i; } v; v.f = f;
    unsigned int r = v.i + 0x7FFFu + ((v.i >> 16) & 1u);   // RNE
    return (ushort_t)(r >> 16);
}
__device__ __forceinline__ float frcp(float x) {
#if __has_builtin(__builtin_amdgcn_rcpf)
    return __builtin_amdgcn_rcpf(x);
#else
    return 1.0f / x;
#endif
}
__device__ __forceinline__ float softplus_f(float u) {
    return fmaxf(u, 0.f) + __logf(1.f + __expf(-fabsf(u)));
}

// 8 contiguous elements -> bf16 short8 (for LDS staging)
__device__ __forceinline__ short8 ld8bf(const ushort_t* p) {
    return *(const short8*)p;
}
__device__ __forceinline__ short8 ld8bf(const float* p) {
    f32x4 a = ((const f32x4*)p)[0];
    f32x4 b = ((const f32x4*)p)[1];
    short8 r;
    r[0] = (short)f2bf(a[0]); r[1] = (short)f2bf(a[1]);
    r[2] = (short)f2bf(a[2]); r[3] = (short)f2bf(a[3]);
    r[4] = (short)f2bf(b[0]); r[5] = (short)f2bf(b[1]);
    r[6] = (short)f2bf(b[2]); r[7] = (short)f2bf(b[3]);
    return r;
}
__device__ __forceinline__ void st1(float* p, float v)    { *p = v; }
__device__ __forceinline__ void st1(ushort_t* p, float v) { *p = f2bf(v); }

// ---------------------------------------------------------------------------
// GEMM: C[M,N] = A[M,K] @ B[N,K]^T (unchanged — known correct).
// ---------------------------------------------------------------------------
template<int K, typename TA, typename TB, typename TC>
__global__ __launch_bounds__(256) void gemm_bt(const TA* __restrict__ A,
                                               const TB* __restrict__ B,
                                               TC* __restrict__ C, int N) {
    __shared__ alignas(16) ushort_t As[128][40];
    __shared__ alignas(16) ushort_t Bs[128][40];
    const int tid  = threadIdx.x;
    const int wave = tid >> 6, lane = tid & 63;
    const int wm = (wave >> 1) * 64, wn = (wave & 1) * 64;
    const int row0 = blockIdx.y * 128, col0 = blockIdx.x * 128;
    f32x4 acc[4][4] = {};
    const int srow = tid >> 2;
    const int sk   = (tid & 3) * 8;
    const int fr   = lane & 15;
    const int fk   = (lane >> 4) * 8;
    for (int k0 = 0; k0 < K; k0 += 32) {
        *(short8*)&As[srow][sk]      = ld8bf(&A[(size_t)(row0 + srow)      * K + k0 + sk]);
        *(short8*)&As[srow + 64][sk] = ld8bf(&A[(size_t)(row0 + srow + 64) * K + k0 + sk]);
        *(short8*)&Bs[srow][sk]      = ld8bf(&B[(size_t)(col0 + srow)      * K + k0 + sk]);
        *(short8*)&Bs[srow + 64][sk] = ld8bf(&B[(size_t)(col0 + srow + 64) * K + k0 + sk]);
        __syncthreads();
        short8 af[4], bfr[4];
        #pragma unroll
        for (int i = 0; i < 4; ++i) {
            af[i]  = *(const short8*)&As[wm + i * 16 + fr][fk];
            bfr[i] = *(const short8*)&Bs[wn + i * 16 + fr][fk];
        }
        #pragma unroll
        for (int i = 0; i < 4; ++i)
            #pragma unroll
            for (int j = 0; j < 4; ++j)
                acc[i][j] = __builtin_amdgcn_mfma_f32_16x16x32_bf16(af[i], bfr[j], acc[i][j], 0, 0, 0);
        __syncthreads();
    }
    const int quad = lane >> 4;
    #pragma unroll
    for (int i = 0; i < 4; ++i)
        #pragma unroll
        for (int j = 0; j < 4; ++j)
            #pragma unroll
            for (int r = 0; r < 4; ++r) {
                int row = row0 + wm + i * 16 + quad * 4 + r;
                int col = col0 + wn + j * 16 + fr;
                st1(&C[(size_t)row * N + col], acc[i][j][r]);
            }
}

// ---------------------------------------------------------------------------
// Depthwise causal conv (k=4) + bias + SiLU (unchanged).
// ---------------------------------------------------------------------------
__global__ __launch_bounds__(256) void conv_silu_k(const ushort_t* __restrict__ xz,
                                                   const float* __restrict__ cw,
                                                   const float* __restrict__ cb,
                                                   ushort_t* __restrict__ xc) {
    int idx = blockIdx.x * 256 + threadIdx.x;
    int d4  = (idx & (D_INNER / 4 - 1)) * 4;
    int row = idx >> 9;
    int t   = row & (SEQLEN - 1);
    float a[4] = {0.f, 0.f, 0.f, 0.f};
    #pragma unroll
    for (int j = 0; j < 4; ++j) {
        int tt = t - 3 + j;
        if (tt >= 0) {
            const ushort_t* p = &xz[(size_t)(row - 3 + j) * (2 * D_INNER) + d4];
            #pragma unroll
            for (int u = 0; u < 4; ++u)
                a[u] += cw[(d4 + u) * 4 + j] * bf2f(p[u]);
        }
    }
    #pragma unroll
    for (int u = 0; u < 4; ++u) {
        float v  = a[u] + cb[d4 + u];
        float sv = v / (1.f + expf(-v));
        xc[(size_t)row * D_INNER + d4 + u] = f2bf(sv);
    }
}

// ---------------------------------------------------------------------------
// x_proj (unchanged).
// ---------------------------------------------------------------------------
__global__ __launch_bounds__(256) void xproj_k(const ushort_t* __restrict__ xc,
                                               const float* __restrict__ w,
                                               float* __restrict__ xp) {
    int row  = blockIdx.x * 4 + (threadIdx.x >> 6);
    int lane = threadIdx.x & 63;
    const ushort_t* xr = xc + (size_t)row * D_INNER;
    float xf[32];
    #pragma unroll
    for (int c = 0; c < 4; ++c) {
        short8 xv = *(const short8*)&xr[c * 512 + lane * 8];
        #pragma unroll
        for (int u = 0; u < 8; ++u) xf[c * 8 + u] = bf2f((ushort_t)xv[u]);
    }
    for (int j = 0; j < 33; ++j) {
        float acc = 0.f;
        #pragma unroll
        for (int c = 0; c < 4; ++c) {
            const f32x4* wp = (const f32x4*)&w[(size_t)j * D_INNER + c * 512 + lane * 8];
            f32x4 w0 = wp[0], w1 = wp[1];
            #pragma unroll
            for (int u = 0; u < 4; ++u) acc += xf[c * 8 + u]     * w0[u];
            #pragma unroll
            for (int u = 0; u < 4; ++u) acc += xf[c * 8 + 4 + u] * w1[u];
        }
        acc += __shfl_xor(acc, 32); acc += __shfl_xor(acc, 16);
        acc += __shfl_xor(acc, 8);  acc += __shfl_xor(acc, 4);
        acc += __shfl_xor(acc, 2);  acc += __shfl_xor(acc, 1);
        if (lane == 0) xp[(size_t)row * 33 + j] = acc;
    }
}

// ---------------------------------------------------------------------------
// NEW: per-(row,d) delta = softplus(xp0*dtw+dtb)  (fp32, OVERLAYS xz — xi
// half is dead after conv, z half is consumed here first, barrier-protected;
// one block per row so __syncthreads covers all readers of that row), and
// gz = silu(z) (bf16).  Removes the 16x-redundant softplus and the masked
// silu epilogue from both scan passes.
// ---------------------------------------------------------------------------
__global__ __launch_bounds__(256) void delta_gate_k(const float* __restrict__ xp,
                                                    const float* __restrict__ dtw,
                                                    const float* __restrict__ dtb,
                                                    ushort_t* xz_rw,
                                                    float* delta_out,
                                                    ushort_t* __restrict__ gz) {
    const int row = blockIdx.x;
    const int tid = threadIdx.x;
    const float xp0 = xp[(size_t)row * 33];
    float zv[8];
    #pragma unroll
    for (int i = 0; i < 8; ++i)
        zv[i] = bf2f(xz_rw[(size_t)row * (2 * D_INNER) + D_INNER + tid + 256 * i]);
    __syncthreads();            // all z reads of this row done before overwrite
    #pragma unroll
    for (int i = 0; i < 8; ++i) {
        const int d = tid + 256 * i;
        const float u = fmaf(xp0, dtw[d], dtb[d]);
        delta_out[(size_t)row * D_INNER + d] = softplus_f(u);
        const float z = zv[i];
        gz[(size_t)row * D_INNER + d] = f2bf(z * frcp(1.f + __expf(-z)));
    }
}

// ---------------------------------------------------------------------------
// Chunk-parallel selective scan (delta precomputed).  Per-chunk recurrence is
// affine in entering state h0: h_end = P*h0 + q.  Numerics identical to the
// round-3 passing kernel (delta hoisted bitwise-identically to fp32 buffer).
// ---------------------------------------------------------------------------
__global__ __launch_bounds__(256) void scan_p1(const ushort_t* __restrict__ xc,
                                               const float* __restrict__ delta_,
                                               const float* __restrict__ xp,
                                               const float* __restrict__ A_log,
                                               float* __restrict__ Pbuf,
                                               float* __restrict__ qbuf) {
    const int tid = threadIdx.x;
    const int s   = tid & 15;
    const int ch  = blockIdx.x * 16 + (tid >> 4);
    const int c   = blockIdx.y;
    const int b   = ch >> 11;
    const int d   = ch & (D_INNER - 1);
    const float A_s = -__expf(A_log[s]);
    const int rowbase = b * SEQLEN + c * CHUNKT;
    const float*    dr  = delta_ + (size_t)rowbase * D_INNER + d;
    const float*    Br  = xp + (size_t)rowbase * 33 + 1 + s;
    const ushort_t* xcr = xc + (size_t)rowbase * D_INNER + d;
    float Acum = 1.f, wc = 0.f, prevA = 1.f;
    #pragma unroll 4
    for (int t = 0; t < CHUNKT; ++t) {
        const float dv  = dr[0];
        const float Bv  = Br[0];
        const float xcv = bf2f(xcr[0]);
        const float Ab  = fmaxf(__expf(dv * A_s), EPSF);
        prevA = Acum;
        Acum  = prevA * Ab;
        wc    = fmaf(dv * Bv * xcv, frcp(fmaxf(prevA, EPSF)), wc);
        dr += D_INNER; Br += 33; xcr += D_INNER;
    }
    const size_t base = ((size_t)c * NCH + ch) * 16 + s;
    Pbuf[base] = Acum;
    qbuf[base] = prevA * wc;
}

__global__ __launch_bounds__(256) void combine_k(const float* __restrict__ Pbuf,
                                                 const float* __restrict__ qbuf,
                                                 float* __restrict__ hbuf) {
    const int i = blockIdx.x * 256 + threadIdx.x;
    float h = 0.f;
    #pragma unroll
    for (int c = 0; c < NCHUNK; ++c) {
        const size_t idx = (size_t)c * (NCH * 16) + i;
        hbuf[idx] = h;                               // state ENTERING chunk c
        h = fmaf(Pbuf[idx], h, qbuf[idx]);
    }
}

__global__ __launch_bounds__(256) void scan_p2(const ushort_t* __restrict__ xc,
                                               const float* __restrict__ delta_,
                                               const float* __restrict__ xp,
                                               const ushort_t* __restrict__ gz,
                                               const float* __restrict__ A_log,
                                               const float* __restrict__ D_par,
                                               const float* __restrict__ hbuf,
                                               ushort_t* __restrict__ G) {
    const int tid = threadIdx.x;
    const int s   = tid & 15;
    const int ch  = blockIdx.x * 16 + (tid >> 4);
    const int c   = blockIdx.y;
    const int b   = ch >> 11;
    const int d   = ch & (D_INNER - 1);
    const float A_s = -__expf(A_log[s]);
    const float Dp  = D_par[d];
    const float h0  = hbuf[((size_t)c * NCH + ch) * 16 + s];
    const int rowbase = b * SEQLEN + c * CHUNKT;
    const float*    dr  = delta_ + (size_t)rowbase * D_INNER + d;
    const float*    xpr = xp + (size_t)rowbase * 33;
    const ushort_t* xcr = xc + (size_t)rowbase * D_INNER + d;
    const ushort_t* gzr = gz + (size_t)rowbase * D_INNER + d;
    ushort_t*       Gr  = G  + (size_t)rowbase * D_INNER + d;
    float Acum = 1.f, wc = 0.f;
    #pragma unroll 4
    for (int t = 0; t < CHUNKT; ++t) {
        const float dv  = dr[0];
        const float Bv  = xpr[1 + s];
        const float Cv  = xpr[17 + s];
        const float xcv = bf2f(xcr[0]);
        const float Ab  = fmaxf(__expf(dv * A_s), EPSF);
        const float prevA = Acum;
        Acum = prevA * Ab;
        wc   = fmaf(dv * Bv * xcv, frcp(fmaxf(prevA, EPSF)), wc);
        const float h  = fmaf(prevA, wc, h0 * Acum);
        float ys = Cv * h;
        ys += __shfl_xor(ys, 1); ys += __shfl_xor(ys, 2);
        ys += __shfl_xor(ys, 4); ys += __shfl_xor(ys, 8);
        if (s == 0) {
            const float y = fmaf(Dp, xcv, ys);
            Gr[0] = f2bf(y * bf2f(gzr[0]));
        }
        dr += D_INNER; xpr += 33; xcr += D_INNER; gzr += D_INNER; Gr += D_INNER;
    }
}

// ---------------------------------------------------------------------------
extern "C" void kernel_launch(void* const* d_in, const int* in_sizes, int n_in,
                              void* d_out, int out_size, void* d_ws, size_t ws_size,
                              hipStream_t stream) {
    const float* x     = (const float*)d_in[0];
    const float* w_in  = (const float*)d_in[1];
    const float* cw    = (const float*)d_in[2];
    const float* cb    = (const float*)d_in[3];
    const float* w_xp  = (const float*)d_in[4];
    const float* dtw   = (const float*)d_in[5];
    const float* dtb   = (const float*)d_in[6];
    const float* alog  = (const float*)d_in[7];
    const float* dpar  = (const float*)d_in[8];
    const float* w_out = (const float*)d_in[9];
    float* out = (float*)d_out;

    char* ws = (char*)d_ws;
    const size_t MB = 1024ull * 1024ull;
    ushort_t* xz    = (ushort_t*)ws;                 // 32 MiB (xi|z), then delta overlays
    float*    delta = (float*)ws;                    // 32 MiB fp32, SAME region as xz
    ushort_t* xc    = (ushort_t*)(ws + 32 * MB);     // 16 MiB
    float*    xp    = (float*)   (ws + 48 * MB);     // 0.54 MiB
    float*    Pbuf  = (float*)   (ws + 49 * MB);     // 2 MiB
    float*    qbuf  = (float*)   (ws + 51 * MB);     // 2 MiB
    float*    hbuf  = (float*)   (ws + 53 * MB);     // 2 MiB
    ushort_t* gz    = (ushort_t*)(ws + 55 * MB);     // 16 MiB  (total 71 MiB)
    ushort_t* G     = xc;                            // in-place over xc

    // 1) xz = x @ in_proj_w^T   (M=4096, N=4096, K=1024)
    hipLaunchKernelGGL((gemm_bt<D_MODEL, float, float, ushort_t>),
                       dim3(2 * D_INNER / 128, NROW / 128), dim3(256), 0, stream,
                       x, w_in, xz, 2 * D_INNER);
    // 2) xc = silu(causal depthwise conv(xi) + cb)
    hipLaunchKernelGGL(conv_silu_k, dim3(NROW * (D_INNER / 4) / 256), dim3(256), 0, stream,
                       xz, cw, cb, xc);
    // 3) xp = xc @ x_proj_w^T
    hipLaunchKernelGGL(xproj_k, dim3(NROW / 4), dim3(256), 0, stream, xc, w_xp, xp);
    // 3b) delta (over xz) + gz = silu(z)
    hipLaunchKernelGGL(delta_gate_k, dim3(NROW), dim3(256), 0, stream,
                       xp, dtw, dtb, xz, delta, gz);
    // 4a) per-chunk (P,q)
    hipLaunchKernelGGL(scan_p1, dim3(NCH / 16, NCHUNK), dim3(256), 0, stream,
                       xc, delta, xp, alog, Pbuf, qbuf);
    // 4b) chunk chain -> h0 per chunk
    hipLaunchKernelGGL(combine_k, dim3(NCH * 16 / 256), dim3(256), 0, stream,
                       Pbuf, qbuf, hbuf);
    // 4c) replay with h0, emit G (in place over xc)
    hipLaunchKernelGGL(scan_p2, dim3(NCH / 16, NCHUNK), dim3(256), 0, stream,
                       xc, delta, xp, gz, alog, dpar, hbuf, G);
    // 5) out = G @ out_proj_w^T  (M=4096, N=1024, K=2048)
    hipLaunchKernelGGL((gemm_bt<D_INNER, ushort_t, float, float>),
                       dim3(D_MODEL / 128, NROW / 128), dim3(256), 0, stream,
                       G, w_out, out, D_MODEL);
    (void)in_sizes; (void)n_in; (void)out_size; (void)ws_size;
}